// Round 2
// baseline (235.854 us; speedup 1.0000x reference)
//
#include <hip/hip_runtime.h>
#include <hip/hip_bf16.h>
#include <stdint.h>

// B=4, M=256, N=64, D=512, C=1024
// out[b,m,n,c] = log_softmax_c( tanh(pe[b,m,:] + pd[b,n,:]) . W2[c,:] + b2[c] )
// pe = enc @ W1[:, :D]^T ; pd = dec @ W1[:, D:]^T + b1

typedef __bf16         bf16x8 __attribute__((ext_vector_type(8)));
typedef float          f32x4  __attribute__((ext_vector_type(4)));
typedef unsigned short u16x8  __attribute__((ext_vector_type(8)));

__device__ __forceinline__ unsigned short f2bf(float f) {
  unsigned int u = __float_as_uint(f);
  u += 0x7fffu + ((u >> 16) & 1u);          // RNE
  return (unsigned short)(u >> 16);
}

__device__ __forceinline__ f32x4 mfma16(u16x8 a, u16x8 b, f32x4 c) {
  return __builtin_amdgcn_mfma_f32_16x16x32_bf16(
      __builtin_bit_cast(bf16x8, a), __builtin_bit_cast(bf16x8, b), c, 0, 0, 0);
}

// ---------------- prep: f32 -> bf16 conversions ----------------
// enc: 524288 el, dec: 131072 el, W1 halves: 262144 el each, W2: 524288 el
__global__ __launch_bounds__(256) void prep_kernel(
    const float* __restrict__ enc, const float* __restrict__ dec,
    const float* __restrict__ W1,  const float* __restrict__ W2,
    unsigned short* __restrict__ encB, unsigned short* __restrict__ decB,
    unsigned short* __restrict__ W1eB, unsigned short* __restrict__ W1dB,
    unsigned short* __restrict__ W2B)
{
  const int i = blockIdx.x * 256 + threadIdx.x;   // 0 .. 524287
  encB[i] = f2bf(enc[i]);
  W2B[i]  = f2bf(W2[i]);
  if (i < 262144) {                                // W1 is [512][1024]
    const int k = i >> 9, d = i & 511;
    W1eB[i] = f2bf(W1[k * 1024 + d]);
    W1dB[i] = f2bf(W1[k * 1024 + 512 + d]);
  }
  if (i < 131072) decB[i] = f2bf(dec[i]);
}

// ---------------- proj: out[r][c] = sum_d A[r][d]*Wt[c][d] (+bias[c]) ----------------
// A: [nrows][512] bf16, Wt: [512][512] bf16, out: [nrows][512] f32
// grid = (nrows/64)*8, block = 256 (4 waves, each 64 rows x 16 cols)
__global__ __launch_bounds__(256) void proj_kernel(
    const unsigned short* __restrict__ A, const unsigned short* __restrict__ Wt,
    const float* __restrict__ bias, float* __restrict__ out)
{
  const int rtile = blockIdx.x >> 3;
  const int ctile = blockIdx.x & 7;
  const int w = threadIdx.x >> 6;
  const int l = threadIdx.x & 63;
  const int q = l >> 4, ln = l & 15;

  f32x4 acc[4] = {};
  const unsigned short* Ab = A  + (size_t)(rtile * 64 + ln) * 512 + q * 8;
  const unsigned short* Wb = Wt + (size_t)(ctile * 64 + w * 16 + ln) * 512 + q * 8;

#pragma unroll 4
  for (int ks = 0; ks < 16; ++ks) {
    u16x8 bv = *(const u16x8*)(Wb + ks * 32);
#pragma unroll
    for (int rf = 0; rf < 4; ++rf) {
      u16x8 av = *(const u16x8*)(Ab + rf * 16 * 512 + ks * 32);
      acc[rf] = mfma16(av, bv, acc[rf]);
    }
  }
  const int col = ctile * 64 + w * 16 + ln;
  const float bv = bias ? bias[col] : 0.0f;
#pragma unroll
  for (int rf = 0; rf < 4; ++rf)
#pragma unroll
    for (int j = 0; j < 4; ++j)
      out[(size_t)(rtile * 64 + rf * 16 + q * 4 + j) * 512 + col] = acc[rf][j] + bv;
}

// ---------------- joint: fused tanh-GEMM + bias + log_softmax ----------------
// grid = B*M = 1024 blocks, block = 512 threads (8 waves).
// Block computes rows n=0..63 (for its (b,m)) x cols 0..1023, then log_softmax over cols.
__global__ __launch_bounds__(512) void joint_kernel(
    const float* __restrict__ pe, const float* __restrict__ pd,
    const unsigned short* __restrict__ W2B, const float* __restrict__ b2,
    float* __restrict__ out)
{
  __shared__ unsigned short A_sh[64 * 512];   // 64 KiB, XOR-swizzled bf16 tile
  __shared__ float red_max[8][64];
  __shared__ float red_sum[8][64];

  const int blk = blockIdx.x;            // b*256 + m
  const int b   = blk >> 8;
  const int tid = threadIdx.x;
  const int w = tid >> 6, l = tid & 63;
  const int q = l >> 4, ln = l & 15;

  // ---- generate A[n][d] = tanh(pe[m,d] + pd[n,d]) into swizzled LDS ----
  {
    const int n  = tid >> 3;               // 0..63
    const int d0 = (tid & 7) * 64;
    const float* per = pe + (size_t)blk * 512;
    const float* pdr = pd + (size_t)(b * 64 + n) * 512;
    char* rowbase = (char*)A_sh + n * 1024;
#pragma unroll
    for (int it = 0; it < 8; ++it) {
      const int d = d0 + it * 8;
      float4 p0 = *(const float4*)(per + d);
      float4 p1 = *(const float4*)(per + d + 4);
      float4 q0 = *(const float4*)(pdr + d);
      float4 q1 = *(const float4*)(pdr + d + 4);
      float x[8] = {p0.x + q0.x, p0.y + q0.y, p0.z + q0.z, p0.w + q0.w,
                    p1.x + q1.x, p1.y + q1.y, p1.z + q1.z, p1.w + q1.w};
      u16x8 pk;
#pragma unroll
      for (int e = 0; e < 8; ++e) {
        const float ex = __expf(2.0f * x[e]);      // tanh(x) = 1 - 2/(e^{2x}+1)
        const float t  = 1.0f - 2.0f / (ex + 1.0f);
        pk[e] = f2bf(t);
      }
      const int s = d >> 3;                        // 16B slot index within row
      *(u16x8*)(rowbase + (((s ^ (n & 7)) << 4))) = pk;
    }
  }
  __syncthreads();

  // ---- GEMM: wave w owns cols [w*128, w*128+128), rows 0..63 ----
  f32x4 acc[4][8];
#pragma unroll
  for (int rf = 0; rf < 4; ++rf)
#pragma unroll
    for (int cf = 0; cf < 8; ++cf) acc[rf][cf] = (f32x4){0.f, 0.f, 0.f, 0.f};

  const char* Abase = (const char*)A_sh + ln * 1024;               // + rf*16384
  const unsigned short* Wb = W2B + (size_t)(w * 128 + ln) * 512 + q * 8;  // + cf*8192 + ks*32
  const int xr = l & 7;

  for (int ks = 0; ks < 16; ++ks) {
    u16x8 av[4], bv[8];
#pragma unroll
    for (int rf = 0; rf < 4; ++rf)
      av[rf] = *(const u16x8*)(Abase + rf * 16384 + (((ks * 4 + q) ^ xr) << 4));
#pragma unroll
    for (int cf = 0; cf < 8; ++cf)
      bv[cf] = *(const u16x8*)(Wb + cf * 8192 + ks * 32);
#pragma unroll
    for (int rf = 0; rf < 4; ++rf)
#pragma unroll
      for (int cf = 0; cf < 8; ++cf)
        acc[rf][cf] = mfma16(av[rf], bv[cf], acc[rf][cf]);
  }

  // ---- epilogue: + b2, log_softmax over the 1024 cols of each row ----
  float b2v[8];
#pragma unroll
  for (int cf = 0; cf < 8; ++cf) b2v[cf] = b2[w * 128 + cf * 16 + ln];
#pragma unroll
  for (int rf = 0; rf < 4; ++rf)
#pragma unroll
    for (int cf = 0; cf < 8; ++cf)
#pragma unroll
      for (int j = 0; j < 4; ++j) acc[rf][cf][j] += b2v[cf];

  // per-thread rows: row = rf*16 + q*4 + j  (16 rows), cols: cf*16 + ln (8 cols)
  float mx[4][4];
#pragma unroll
  for (int rf = 0; rf < 4; ++rf)
#pragma unroll
    for (int j = 0; j < 4; ++j) {
      float m = acc[rf][0][j];
#pragma unroll
      for (int cf = 1; cf < 8; ++cf) m = fmaxf(m, acc[rf][cf][j]);
      mx[rf][j] = m;
    }
#pragma unroll
  for (int o = 1; o < 16; o <<= 1)
#pragma unroll
    for (int rf = 0; rf < 4; ++rf)
#pragma unroll
      for (int j = 0; j < 4; ++j)
        mx[rf][j] = fmaxf(mx[rf][j], __shfl_xor(mx[rf][j], o));
  if (ln == 0) {
#pragma unroll
    for (int rf = 0; rf < 4; ++rf)
#pragma unroll
      for (int j = 0; j < 4; ++j) red_max[w][rf * 16 + q * 4 + j] = mx[rf][j];
  }
  __syncthreads();

  float fmx[4][4], sm[4][4];
#pragma unroll
  for (int rf = 0; rf < 4; ++rf)
#pragma unroll
    for (int j = 0; j < 4; ++j) {
      const int row = rf * 16 + q * 4 + j;
      float m = red_max[0][row];
#pragma unroll
      for (int ww = 1; ww < 8; ++ww) m = fmaxf(m, red_max[ww][row]);
      fmx[rf][j] = m;
      float s = 0.f;
#pragma unroll
      for (int cf = 0; cf < 8; ++cf) s += __expf(acc[rf][cf][j] - m);
      sm[rf][j] = s;
    }
#pragma unroll
  for (int o = 1; o < 16; o <<= 1)
#pragma unroll
    for (int rf = 0; rf < 4; ++rf)
#pragma unroll
      for (int j = 0; j < 4; ++j)
        sm[rf][j] += __shfl_xor(sm[rf][j], o);
  if (ln == 0) {
#pragma unroll
    for (int rf = 0; rf < 4; ++rf)
#pragma unroll
      for (int j = 0; j < 4; ++j) red_sum[w][rf * 16 + q * 4 + j] = sm[rf][j];
  }
  __syncthreads();

  float* outb = out + (size_t)blk * (64 * 1024) + w * 128 + ln;
#pragma unroll
  for (int rf = 0; rf < 4; ++rf)
#pragma unroll
    for (int j = 0; j < 4; ++j) {
      const int row = rf * 16 + q * 4 + j;
      float s = red_sum[0][row];
#pragma unroll
      for (int ww = 1; ww < 8; ++ww) s += red_sum[ww][row];
      const float lse = fmx[rf][j] + __logf(s);
      float* orow = outb + (size_t)row * 1024;
#pragma unroll
      for (int cf = 0; cf < 8; ++cf) orow[cf * 16] = acc[rf][cf][j] - lse;
    }
}

extern "C" void kernel_launch(void* const* d_in, const int* in_sizes, int n_in,
                              void* d_out, int out_size, void* d_ws, size_t ws_size,
                              hipStream_t stream) {
  (void)in_sizes; (void)n_in; (void)out_size; (void)ws_size;
  const float* enc = (const float*)d_in[0];
  const float* dec = (const float*)d_in[1];
  const float* W1  = (const float*)d_in[2];
  const float* b1  = (const float*)d_in[3];
  const float* W2  = (const float*)d_in[4];
  const float* b2  = (const float*)d_in[5];
  float* out = (float*)d_out;

  char* ws = (char*)d_ws;
  unsigned short* encB = (unsigned short*)(ws + 0);        // 1 MiB   (524288 el)
  unsigned short* decB = (unsigned short*)(ws + 1048576);  // 256 KiB (131072 el)
  unsigned short* W1eB = (unsigned short*)(ws + 1310720);  // 512 KiB (262144 el)
  unsigned short* W1dB = (unsigned short*)(ws + 1835008);  // 512 KiB (262144 el)
  unsigned short* W2B  = (unsigned short*)(ws + 2359296);  // 1 MiB   (524288 el)
  float*          pe   = (float*)(ws + 3407872);           // 2 MiB  [1024][512]
  float*          pd   = (float*)(ws + 5505024);           // 512 KiB [256][512]

  prep_kernel<<<2048, 256, 0, stream>>>(enc, dec, W1, W2, encB, decB, W1eB, W1dB, W2B);
  proj_kernel<<<128, 256, 0, stream>>>(encB, W1eB, nullptr, pe);   // pe: 1024x512
  proj_kernel<<< 32, 256, 0, stream>>>(decB, W1dB, b1,      pd);   // pd:  256x512
  joint_kernel<<<1024, 512, 0, stream>>>(pe, pd, W2B, b2, out);
}

// Round 3
// 218.636 us; speedup vs baseline: 1.0788x; 1.0788x over previous
//
#include <hip/hip_runtime.h>
#include <hip/hip_bf16.h>
#include <stdint.h>

// B=4, M=256, N=64, D=512, C=1024
// out[b,m,n,c] = log_softmax_c( tanh(pe[b,m,:] + pd[b,n,:]) . W2[c,:] + b2[c] )
// pe = enc @ W1[:, :D]^T ; pd = dec @ W1[:, D:]^T + b1

typedef __bf16         bf16x8 __attribute__((ext_vector_type(8)));
typedef float          f32x4  __attribute__((ext_vector_type(4)));
typedef unsigned short u16x8  __attribute__((ext_vector_type(8)));

__device__ __forceinline__ unsigned short f2bf(float f) {
  unsigned int u = __float_as_uint(f);
  u += 0x7fffu + ((u >> 16) & 1u);          // RNE
  return (unsigned short)(u >> 16);
}

__device__ __forceinline__ f32x4 mfma16(u16x8 a, u16x8 b, f32x4 c) {
  return __builtin_amdgcn_mfma_f32_16x16x32_bf16(
      __builtin_bit_cast(bf16x8, a), __builtin_bit_cast(bf16x8, b), c, 0, 0, 0);
}

// ---------------- prep: f32 -> bf16 conversions ----------------
// enc: 524288 el, dec: 131072 el, W1 halves: 262144 el each, W2: 524288 el
__global__ __launch_bounds__(256) void prep_kernel(
    const float* __restrict__ enc, const float* __restrict__ dec,
    const float* __restrict__ W1,  const float* __restrict__ W2,
    unsigned short* __restrict__ encB, unsigned short* __restrict__ decB,
    unsigned short* __restrict__ W1eB, unsigned short* __restrict__ W1dB,
    unsigned short* __restrict__ W2B)
{
  const int i = blockIdx.x * 256 + threadIdx.x;   // 0 .. 524287
  encB[i] = f2bf(enc[i]);
  W2B[i]  = f2bf(W2[i]);
  if (i < 262144) {                                // W1 is [512][1024]
    const int k = i >> 9, d = i & 511;
    W1eB[i] = f2bf(W1[k * 1024 + d]);
    W1dB[i] = f2bf(W1[k * 1024 + 512 + d]);
  }
  if (i < 131072) decB[i] = f2bf(dec[i]);
}

// ---------------- proj: out[r][c] = sum_d A[r][d]*Wt[c][d] (+bias[c]) ----------------
__global__ __launch_bounds__(256) void proj_kernel(
    const unsigned short* __restrict__ A, const unsigned short* __restrict__ Wt,
    const float* __restrict__ bias, float* __restrict__ out)
{
  const int rtile = blockIdx.x >> 3;
  const int ctile = blockIdx.x & 7;
  const int w = threadIdx.x >> 6;
  const int l = threadIdx.x & 63;
  const int q = l >> 4, ln = l & 15;

  f32x4 acc[4] = {};
  const unsigned short* Ab = A  + (size_t)(rtile * 64 + ln) * 512 + q * 8;
  const unsigned short* Wb = Wt + (size_t)(ctile * 64 + w * 16 + ln) * 512 + q * 8;

#pragma unroll 4
  for (int ks = 0; ks < 16; ++ks) {
    u16x8 bv = *(const u16x8*)(Wb + ks * 32);
#pragma unroll
    for (int rf = 0; rf < 4; ++rf) {
      u16x8 av = *(const u16x8*)(Ab + rf * 16 * 512 + ks * 32);
      acc[rf] = mfma16(av, bv, acc[rf]);
    }
  }
  const int col = ctile * 64 + w * 16 + ln;
  const float bv = bias ? bias[col] : 0.0f;
#pragma unroll
  for (int rf = 0; rf < 4; ++rf)
#pragma unroll
    for (int j = 0; j < 4; ++j)
      out[(size_t)(rtile * 64 + rf * 16 + q * 4 + j) * 512 + col] = acc[rf][j] + bv;
}

// ---------------- joint: fused tanh-GEMM + bias + log_softmax ----------------
// grid = B*M = 1024 blocks, block = 512 threads (8 waves).
__global__ __launch_bounds__(512) void joint_kernel(
    const float* __restrict__ pe, const float* __restrict__ pd,
    const unsigned short* __restrict__ W2B, const float* __restrict__ b2,
    float* __restrict__ out)
{
  __shared__ unsigned short A_sh[64 * 512];   // 64 KiB, XOR-swizzled bf16 tile
  __shared__ float red_max[8][64];
  __shared__ float red_sum[8][64];

  const int blk = blockIdx.x;            // b*256 + m
  const int b   = blk >> 8;
  const int tid = threadIdx.x;
  const int w = tid >> 6, l = tid & 63;
  const int q = l >> 4, ln = l & 15;

  // hoist B (W2) ks=0 loads + b2 — independent of the A tile
  const unsigned short* Wb = W2B + (size_t)(w * 128 + ln) * 512 + q * 8;  // + cf*8192 + ks*32
  u16x8 b_c[8], b_n[8];
#pragma unroll
  for (int cf = 0; cf < 8; ++cf) b_c[cf] = *(const u16x8*)(Wb + cf * 8192);
  float b2v[8];
#pragma unroll
  for (int cf = 0; cf < 8; ++cf) b2v[cf] = b2[w * 128 + cf * 16 + ln];

  // ---- generate A[n][d] = tanh(pe[m,d] + pd[n,d]) into swizzled LDS ----
  // wave w owns rows w*8..w*8+7; lane l owns d = l*8..l*8+7 (coalesced 1KB loads)
  {
    const float* per = pe + (size_t)blk * 512 + l * 8;
    const float4 pe0 = *(const float4*)(per);
    const float4 pe1 = *(const float4*)(per + 4);
#pragma unroll
    for (int r = 0; r < 8; ++r) {
      const int n = w * 8 + r;
      const float* pdr = pd + (size_t)(b * 64 + n) * 512 + l * 8;
      const float4 q0 = *(const float4*)(pdr);
      const float4 q1 = *(const float4*)(pdr + 4);
      float x[8] = {pe0.x + q0.x, pe0.y + q0.y, pe0.z + q0.z, pe0.w + q0.w,
                    pe1.x + q1.x, pe1.y + q1.y, pe1.z + q1.z, pe1.w + q1.w};
      u16x8 pk;
#pragma unroll
      for (int e = 0; e < 8; ++e) {
        const float ex = __expf(2.0f * x[e]);      // tanh(x) = 1 - 2/(e^{2x}+1)
        const float t  = 1.0f - 2.0f / (ex + 1.0f);
        pk[e] = f2bf(t);
      }
      // 16B slot l, XOR-swizzled by row: 2-way per quarter-wave (conflict-free)
      *(u16x8*)((char*)A_sh + n * 1024 + ((l ^ (n & 7)) << 4)) = pk;
    }
  }
  __syncthreads();

  // ---- GEMM: wave w owns cols [w*128, w*128+128), rows 0..63 ----
  f32x4 acc[4][8];
#pragma unroll
  for (int rf = 0; rf < 4; ++rf)
#pragma unroll
    for (int cf = 0; cf < 8; ++cf) acc[rf][cf] = (f32x4){0.f, 0.f, 0.f, 0.f};

  const char* Abase = (const char*)A_sh + ln * 1024;   // + rf*16384, row = rf*16+ln
  const int xr = l & 7;                                 // row&7 == ln&7 == l&7

  u16x8 a_c[4], a_n[4];
#pragma unroll
  for (int rf = 0; rf < 4; ++rf)
    a_c[rf] = *(const u16x8*)(Abase + rf * 16384 + ((q ^ xr) << 4));

  for (int ks = 0; ks < 16; ++ks) {
    const int ksn = (ks < 15) ? ks + 1 : 15;   // depth-1 prefetch (tail reloads, harmless)
#pragma unroll
    for (int cf = 0; cf < 8; ++cf)
      b_n[cf] = *(const u16x8*)(Wb + cf * 8192 + ksn * 32);
#pragma unroll
    for (int rf = 0; rf < 4; ++rf)
      a_n[rf] = *(const u16x8*)(Abase + rf * 16384 + (((ksn * 4 + q) ^ xr) << 4));
#pragma unroll
    for (int rf = 0; rf < 4; ++rf)
#pragma unroll
      for (int cf = 0; cf < 8; ++cf)
        acc[rf][cf] = mfma16(a_c[rf], b_c[cf], acc[rf][cf]);
#pragma unroll
    for (int rf = 0; rf < 4; ++rf) a_c[rf] = a_n[rf];
#pragma unroll
    for (int cf = 0; cf < 8; ++cf) b_c[cf] = b_n[cf];
  }

  // ---- epilogue: + b2, log_softmax over the 1024 cols of each row ----
#pragma unroll
  for (int rf = 0; rf < 4; ++rf)
#pragma unroll
    for (int cf = 0; cf < 8; ++cf)
#pragma unroll
      for (int j = 0; j < 4; ++j) acc[rf][cf][j] += b2v[cf];

  // per-thread rows: row = rf*16 + q*4 + j (16 rows), cols: cf*16 + ln (8 cols)
  float mx[4][4];
#pragma unroll
  for (int rf = 0; rf < 4; ++rf)
#pragma unroll
    for (int j = 0; j < 4; ++j) {
      float m = acc[rf][0][j];
#pragma unroll
      for (int cf = 1; cf < 8; ++cf) m = fmaxf(m, acc[rf][cf][j]);
      mx[rf][j] = m;
    }
#pragma unroll
  for (int o = 1; o < 16; o <<= 1)
#pragma unroll
    for (int rf = 0; rf < 4; ++rf)
#pragma unroll
      for (int j = 0; j < 4; ++j)
        mx[rf][j] = fmaxf(mx[rf][j], __shfl_xor(mx[rf][j], o));
  if (ln == 0) {
#pragma unroll
    for (int rf = 0; rf < 4; ++rf)
#pragma unroll
      for (int j = 0; j < 4; ++j) red_max[w][rf * 16 + q * 4 + j] = mx[rf][j];
  }
  __syncthreads();

  float fmx[4][4], sm[4][4];
#pragma unroll
  for (int rf = 0; rf < 4; ++rf)
#pragma unroll
    for (int j = 0; j < 4; ++j) {
      const int row = rf * 16 + q * 4 + j;
      float m = red_max[0][row];
#pragma unroll
      for (int ww = 1; ww < 8; ++ww) m = fmaxf(m, red_max[ww][row]);
      fmx[rf][j] = m;
      float s = 0.f;
#pragma unroll
      for (int cf = 0; cf < 8; ++cf) s += __expf(acc[rf][cf][j] - m);
      sm[rf][j] = s;
    }
#pragma unroll
  for (int o = 1; o < 16; o <<= 1)
#pragma unroll
    for (int rf = 0; rf < 4; ++rf)
#pragma unroll
      for (int j = 0; j < 4; ++j)
        sm[rf][j] += __shfl_xor(sm[rf][j], o);
  if (ln == 0) {
#pragma unroll
    for (int rf = 0; rf < 4; ++rf)
#pragma unroll
      for (int j = 0; j < 4; ++j) red_sum[w][rf * 16 + q * 4 + j] = sm[rf][j];
  }
  __syncthreads();

  float* outb = out + (size_t)blk * (64 * 1024) + w * 128 + ln;
#pragma unroll
  for (int rf = 0; rf < 4; ++rf)
#pragma unroll
    for (int j = 0; j < 4; ++j) {
      const int row = rf * 16 + q * 4 + j;
      float s = red_sum[0][row];
#pragma unroll
      for (int ww = 1; ww < 8; ++ww) s += red_sum[ww][row];
      const float lse = fmx[rf][j] + __logf(s);
      float* orow = outb + (size_t)row * 1024;
#pragma unroll
      for (int cf = 0; cf < 8; ++cf) orow[cf * 16] = acc[rf][cf][j] - lse;
    }
}

extern "C" void kernel_launch(void* const* d_in, const int* in_sizes, int n_in,
                              void* d_out, int out_size, void* d_ws, size_t ws_size,
                              hipStream_t stream) {
  (void)in_sizes; (void)n_in; (void)out_size; (void)ws_size;
  const float* enc = (const float*)d_in[0];
  const float* dec = (const float*)d_in[1];
  const float* W1  = (const float*)d_in[2];
  const float* b1  = (const float*)d_in[3];
  const float* W2  = (const float*)d_in[4];
  const float* b2  = (const float*)d_in[5];
  float* out = (float*)d_out;

  char* ws = (char*)d_ws;
  unsigned short* encB = (unsigned short*)(ws + 0);        // 1 MiB   (524288 el)
  unsigned short* decB = (unsigned short*)(ws + 1048576);  // 256 KiB (131072 el)
  unsigned short* W1eB = (unsigned short*)(ws + 1310720);  // 512 KiB (262144 el)
  unsigned short* W1dB = (unsigned short*)(ws + 1835008);  // 512 KiB (262144 el)
  unsigned short* W2B  = (unsigned short*)(ws + 2359296);  // 1 MiB   (524288 el)
  float*          pe   = (float*)(ws + 3407872);           // 2 MiB  [1024][512]
  float*          pd   = (float*)(ws + 5505024);           // 512 KiB [256][512]

  prep_kernel<<<2048, 256, 0, stream>>>(enc, dec, W1, W2, encB, decB, W1eB, W1dB, W2B);
  proj_kernel<<<128, 256, 0, stream>>>(encB, W1eB, nullptr, pe);   // pe: 1024x512
  proj_kernel<<< 32, 256, 0, stream>>>(decB, W1dB, b1,      pd);   // pd:  256x512
  joint_kernel<<<1024, 512, 0, stream>>>(pe, pd, W2B, b2, out);
}

// Round 4
// 212.880 us; speedup vs baseline: 1.1079x; 1.0270x over previous
//
#include <hip/hip_runtime.h>
#include <hip/hip_bf16.h>
#include <stdint.h>

// B=4, M=256, N=64, D=512, C=1024
// out[b,m,n,c] = log_softmax_c( tanh(pe[b,m,:] + pd[b,n,:]) . W2[c,:] + b2[c] )
// pe = enc @ W1[:, :D]^T ; pd = dec @ W1[:, D:]^T + b1

typedef __bf16         bf16x8 __attribute__((ext_vector_type(8)));
typedef float          f32x4  __attribute__((ext_vector_type(4)));
typedef unsigned short u16x8  __attribute__((ext_vector_type(8)));

__device__ __forceinline__ unsigned short f2bf(float f) {
  unsigned int u = __float_as_uint(f);
  u += 0x7fffu + ((u >> 16) & 1u);          // RNE
  return (unsigned short)(u >> 16);
}

__device__ __forceinline__ f32x4 mfma16(u16x8 a, u16x8 b, f32x4 c) {
  return __builtin_amdgcn_mfma_f32_16x16x32_bf16(
      __builtin_bit_cast(bf16x8, a), __builtin_bit_cast(bf16x8, b), c, 0, 0, 0);
}

// ---------------- prep: f32 -> bf16 conversions ----------------
__global__ __launch_bounds__(256) void prep_kernel(
    const float* __restrict__ enc, const float* __restrict__ dec,
    const float* __restrict__ W1,  const float* __restrict__ W2,
    unsigned short* __restrict__ encB, unsigned short* __restrict__ decB,
    unsigned short* __restrict__ W1eB, unsigned short* __restrict__ W1dB,
    unsigned short* __restrict__ W2B)
{
  const int i = blockIdx.x * 256 + threadIdx.x;   // 0 .. 524287
  encB[i] = f2bf(enc[i]);
  W2B[i]  = f2bf(W2[i]);
  if (i < 262144) {                                // W1 is [512][1024]
    const int k = i >> 9, d = i & 511;
    W1eB[i] = f2bf(W1[k * 1024 + d]);
    W1dB[i] = f2bf(W1[k * 1024 + 512 + d]);
  }
  if (i < 131072) decB[i] = f2bf(dec[i]);
}

// ---------------- proj: out[r][c] = sum_d A[r][d]*Wt[c][d] (+bias[c]) ----------------
__global__ __launch_bounds__(256) void proj_kernel(
    const unsigned short* __restrict__ A, const unsigned short* __restrict__ Wt,
    const float* __restrict__ bias, float* __restrict__ out)
{
  const int rtile = blockIdx.x >> 3;
  const int ctile = blockIdx.x & 7;
  const int w = threadIdx.x >> 6;
  const int l = threadIdx.x & 63;
  const int q = l >> 4, ln = l & 15;

  f32x4 acc[4] = {};
  const unsigned short* Ab = A  + (size_t)(rtile * 64 + ln) * 512 + q * 8;
  const unsigned short* Wb = Wt + (size_t)(ctile * 64 + w * 16 + ln) * 512 + q * 8;

#pragma unroll 4
  for (int ks = 0; ks < 16; ++ks) {
    u16x8 bv = *(const u16x8*)(Wb + ks * 32);
#pragma unroll
    for (int rf = 0; rf < 4; ++rf) {
      u16x8 av = *(const u16x8*)(Ab + rf * 16 * 512 + ks * 32);
      acc[rf] = mfma16(av, bv, acc[rf]);
    }
  }
  const int col = ctile * 64 + w * 16 + ln;
  const float bv = bias ? bias[col] : 0.0f;
#pragma unroll
  for (int rf = 0; rf < 4; ++rf)
#pragma unroll
    for (int j = 0; j < 4; ++j)
      out[(size_t)(rtile * 64 + rf * 16 + q * 4 + j) * 512 + col] = acc[rf][j] + bv;
}

// ---------------- joint: fused tanh-GEMM + bias + log_softmax ----------------
// grid = B*M = 1024 blocks, block = 1024 threads (16 waves).
// Wave w: all 64 rows x cols [w*64, w*64+64). acc = 4x4 f32x4 = 64 f32/thread.
__global__ __launch_bounds__(1024) void joint_kernel(
    const float* __restrict__ pe, const float* __restrict__ pd,
    const unsigned short* __restrict__ W2B, const float* __restrict__ b2,
    float* __restrict__ out)
{
  __shared__ unsigned short A_sh[64 * 512];   // 64 KiB, XOR-swizzled bf16 tile
  __shared__ float2 red[64][16];              // per-row, per-wave (max, sumexp)
  __shared__ float  lse_sh[64];

  const int blk = blockIdx.x;            // b*256 + m
  const int b   = blk >> 8;
  const int tid = threadIdx.x;
  const int w = tid >> 6, l = tid & 63;
  const int q = l >> 4, ln = l & 15;

  // ---- generate A[n][d] = tanh(pe[m,d] + pd[n,d]) into swizzled LDS ----
  // wave w owns rows w*4..w*4+3; lane l owns d = l*8..l*8+7 (coalesced)
  {
    const float* per = pe + (size_t)blk * 512 + l * 8;
    const float4 pe0 = *(const float4*)(per);
    const float4 pe1 = *(const float4*)(per + 4);
#pragma unroll
    for (int r = 0; r < 4; ++r) {
      const int n = w * 4 + r;
      const float* pdr = pd + (size_t)(b * 64 + n) * 512 + l * 8;
      const float4 q0 = *(const float4*)(pdr);
      const float4 q1 = *(const float4*)(pdr + 4);
      float x[8] = {pe0.x + q0.x, pe0.y + q0.y, pe0.z + q0.z, pe0.w + q0.w,
                    pe1.x + q1.x, pe1.y + q1.y, pe1.z + q1.z, pe1.w + q1.w};
      u16x8 pk;
#pragma unroll
      for (int e = 0; e < 8; ++e) {
        const float ex = __expf(2.0f * x[e]);      // tanh(x) = 1 - 2/(e^{2x}+1)
        const float t  = 1.0f - 2.0f / (ex + 1.0f);
        pk[e] = f2bf(t);
      }
      *(u16x8*)((char*)A_sh + n * 1024 + ((l ^ (n & 7)) << 4)) = pk;
    }
  }
  __syncthreads();

  // ---- GEMM: wave w owns cols [w*64, w*64+64), rows 0..63 ----
  f32x4 acc[4][4];
#pragma unroll
  for (int rf = 0; rf < 4; ++rf)
#pragma unroll
    for (int cf = 0; cf < 4; ++cf) acc[rf][cf] = (f32x4){0.f, 0.f, 0.f, 0.f};

  const char* Abase = (const char*)A_sh + ln * 1024;   // + rf*16384, row = rf*16+ln
  const unsigned short* Wb = W2B + (size_t)(w * 64 + ln) * 512 + q * 8;  // + cf*8192 + ks*32
  const int xr = ln & 7;                                // row&7 == ln&7

  for (int ks = 0; ks < 16; ++ks) {
    u16x8 bv[4], av[4];
#pragma unroll
    for (int cf = 0; cf < 4; ++cf)
      bv[cf] = *(const u16x8*)(Wb + cf * 8192 + ks * 32);
#pragma unroll
    for (int rf = 0; rf < 4; ++rf)
      av[rf] = *(const u16x8*)(Abase + rf * 16384 + (((ks * 4 + q) ^ xr) << 4));
#pragma unroll
    for (int rf = 0; rf < 4; ++rf)
#pragma unroll
      for (int cf = 0; cf < 4; ++cf)
        acc[rf][cf] = mfma16(av[rf], bv[cf], acc[rf][cf]);
  }

  // ---- epilogue: + b2, then log_softmax over cols of each row ----
  // thread's elements: rows rf*16 + q*4 + j (16), cols w*64 + cf*16 + ln (4)
  float b2v[4];
#pragma unroll
  for (int cf = 0; cf < 4; ++cf) b2v[cf] = b2[w * 64 + cf * 16 + ln];
#pragma unroll
  for (int rf = 0; rf < 4; ++rf)
#pragma unroll
    for (int cf = 0; cf < 4; ++cf)
#pragma unroll
      for (int j = 0; j < 4; ++j) acc[rf][cf][j] += b2v[cf];

  // per-wave partial (max, sumexp) over this wave's 64 cols, per row
  {
    float mx[4][4], sm[4][4];
#pragma unroll
    for (int rf = 0; rf < 4; ++rf)
#pragma unroll
      for (int j = 0; j < 4; ++j) {
        float m = acc[rf][0][j];
#pragma unroll
        for (int cf = 1; cf < 4; ++cf) m = fmaxf(m, acc[rf][cf][j]);
        mx[rf][j] = m;
      }
#pragma unroll
    for (int o = 1; o < 16; o <<= 1)
#pragma unroll
      for (int rf = 0; rf < 4; ++rf)
#pragma unroll
        for (int j = 0; j < 4; ++j)
          mx[rf][j] = fmaxf(mx[rf][j], __shfl_xor(mx[rf][j], o));
#pragma unroll
    for (int rf = 0; rf < 4; ++rf)
#pragma unroll
      for (int j = 0; j < 4; ++j) {
        float s = 0.f;
#pragma unroll
        for (int cf = 0; cf < 4; ++cf) s += __expf(acc[rf][cf][j] - mx[rf][j]);
        sm[rf][j] = s;
      }
#pragma unroll
    for (int o = 1; o < 16; o <<= 1)
#pragma unroll
      for (int rf = 0; rf < 4; ++rf)
#pragma unroll
        for (int j = 0; j < 4; ++j)
          sm[rf][j] += __shfl_xor(sm[rf][j], o);
    if (ln == 0) {
#pragma unroll
      for (int rf = 0; rf < 4; ++rf)
#pragma unroll
        for (int j = 0; j < 4; ++j)
          red[rf * 16 + q * 4 + j][w] = make_float2(mx[rf][j], sm[rf][j]);
    }
  }
  __syncthreads();

  // merge the 16 wave-partials: quarter q of wave w handles row w*4+q
  {
    const int row = w * 4 + q;
    const float2 v = red[row][ln];
    float m0 = v.x, s = v.y;
    float m = m0;
#pragma unroll
    for (int o = 1; o < 16; o <<= 1) m = fmaxf(m, __shfl_xor(m, o));
    s *= __expf(m0 - m);
#pragma unroll
    for (int o = 1; o < 16; o <<= 1) s += __shfl_xor(s, o);
    if (ln == 0) lse_sh[row] = m + __logf(s);
  }
  __syncthreads();

  // final: out = acc - lse
  float* outb = out + (size_t)blk * (64 * 1024) + w * 64 + ln;
#pragma unroll
  for (int rf = 0; rf < 4; ++rf)
#pragma unroll
    for (int j = 0; j < 4; ++j) {
      const int row = rf * 16 + q * 4 + j;
      const float lse = lse_sh[row];
      float* orow = outb + (size_t)row * 1024;
#pragma unroll
      for (int cf = 0; cf < 4; ++cf) orow[cf * 16] = acc[rf][cf][j] - lse;
    }
}

extern "C" void kernel_launch(void* const* d_in, const int* in_sizes, int n_in,
                              void* d_out, int out_size, void* d_ws, size_t ws_size,
                              hipStream_t stream) {
  (void)in_sizes; (void)n_in; (void)out_size; (void)ws_size;
  const float* enc = (const float*)d_in[0];
  const float* dec = (const float*)d_in[1];
  const float* W1  = (const float*)d_in[2];
  const float* b1  = (const float*)d_in[3];
  const float* W2  = (const float*)d_in[4];
  const float* b2  = (const float*)d_in[5];
  float* out = (float*)d_out;

  char* ws = (char*)d_ws;
  unsigned short* encB = (unsigned short*)(ws + 0);        // 1 MiB   (524288 el)
  unsigned short* decB = (unsigned short*)(ws + 1048576);  // 256 KiB (131072 el)
  unsigned short* W1eB = (unsigned short*)(ws + 1310720);  // 512 KiB (262144 el)
  unsigned short* W1dB = (unsigned short*)(ws + 1835008);  // 512 KiB (262144 el)
  unsigned short* W2B  = (unsigned short*)(ws + 2359296);  // 1 MiB   (524288 el)
  float*          pe   = (float*)(ws + 3407872);           // 2 MiB  [1024][512]
  float*          pd   = (float*)(ws + 5505024);           // 512 KiB [256][512]

  prep_kernel<<<2048, 256, 0, stream>>>(enc, dec, W1, W2, encB, decB, W1eB, W1dB, W2B);
  proj_kernel<<<128, 256, 0, stream>>>(encB, W1eB, nullptr, pe);   // pe: 1024x512
  proj_kernel<<< 32, 256, 0, stream>>>(decB, W1dB, b1,      pd);   // pd:  256x512
  joint_kernel<<<1024, 1024, 0, stream>>>(pe, pd, W2B, b2, out);
}